// Round 9
// baseline (549.820 us; speedup 1.0000x reference)
//
#include <hip/hip_runtime.h>

#define BINS 10
#define TPB  256
#define NBLK 2048

// ws layout (21 dwords): unsigned ticket; float bsum[BINS]; int bcnt[BINS]
// (harness poisons ws to 0xAA before every launch -> zero-kernel inits it)

__global__ __launch_bounds__(64) void ghmc_zero(unsigned* ws) {
    int i = threadIdx.x;
    if (i < 1 + 2 * BINS) ws[i] = 0u;
}

// Direct global->LDS async copy, 16B per lane. LDS dest is wave-uniform base +
// lane*16 (m104/m108 semantics); all lanes pass the same wave-base pointer.
// This frees VGPRs from outstanding loads: bytes-in-flight no longer capped by
// the register file (r8 post-mortem: compiler collapses >2-batch VGPR pipelines
// to demand loads -> 404us; in-flight needed for peak ~7.4KB/CU, VGPR route
// maxes ~2-3KB/CU).
__device__ __forceinline__ void glds16(const void* g, void* l) {
    __builtin_amdgcn_global_load_lds(
        (const __attribute__((address_space(1))) void*)g,
        (__attribute__((address_space(3))) void*)l, 16, 0, 0);
}

// Per-element update (round-4 form, verified absmax=0 / 112us):
// t in {0,1} -> y = p*(1-2t); bce = softplus(y); bin via y >= logit(b/10).
// Cumulative sums S_b, packed 6-bit cumulative counts (<=41/lane) in cLo/cHi.
// Invalid (w==0): ye=-60 -> below all thresholds, softplus(-60)==0.0f exactly.
#define GHMC_ELEM(pk, tk, wk)                                                 \
    do {                                                                      \
        float tm_ = __builtin_fmaf((tk), -2.0f, 1.0f);  /* {1,-1} exact */    \
        float y_  = tm_ * (pk);                                               \
        bool  v_  = ((wk) > 0.0f);                                            \
        float ye_ = v_ ? y_ : -60.0f;                                         \
        float e_  = __expf(-__builtin_fabsf(ye_));      /* (0,1] */           \
        float onep_ = 1.0f + e_;                        /* (1,2]: log exact */\
        float bce_  = __builtin_fmaf(0.69314718055994530942f,                 \
                                     __log2f(onep_),                          \
                                     __builtin_fmaxf(ye_, 0.0f));             \
        S[0] += bce_;                                                         \
        C0   += v_ ? 1 : 0;                                                   \
        _Pragma("unroll")                                                     \
        for (int b_ = 1; b_ <= 5; ++b_) {                                     \
            bool ge_ = (ye_ >= kL[b_ - 1]);                                   \
            S[b_] += ge_ ? bce_ : 0.0f;                                       \
            cLo   += ge_ ? (1u << (6 * (b_ - 1))) : 0u;                       \
        }                                                                     \
        _Pragma("unroll")                                                     \
        for (int b_ = 6; b_ <= 9; ++b_) {                                     \
            bool ge_ = (ye_ >= kL[b_ - 1]);                                   \
            S[b_] += ge_ ? bce_ : 0.0f;                                       \
            cHi   += ge_ ? (1u << (6 * (b_ - 6))) : 0u;                       \
        }                                                                     \
    } while (0)

#define GHMC_ELEM4(P, T, W_)                                                  \
    do {                                                                      \
        GHMC_ELEM((P).x, (T).x, (W_).x);                                      \
        GHMC_ELEM((P).y, (T).y, (W_).y);                                      \
        GHMC_ELEM((P).z, (T).z, (W_).z);                                      \
        GHMC_ELEM((P).w, (T).w, (W_).w);                                      \
    } while (0)

__global__ __launch_bounds__(256) void ghmc_main(
    const float* __restrict__ pred, const float* __restrict__ targ,
    const float* __restrict__ lw,
    unsigned* __restrict__ ticket, float* __restrict__ bsum,
    int* __restrict__ bcnt, float* __restrict__ out, int n) {

    // logit(b/10), b=1..9
    const float kL[9] = { -2.1972246f, -1.3862944f, -0.84729786f, -0.40546511f,
                          0.0f, 0.40546511f, 0.84729786f, 1.3862944f, 2.1972246f };

    // single-buffer LDS stage: 3 arrays x 256 x 16B = 12 KB -> 8 blocks/CU,
    // 32 waves/CU; in-flight ~8x12KB per CU >> 7.4KB needed for peak BW
    __shared__ float4 sP[TPB];
    __shared__ float4 sT[TPB];
    __shared__ float4 sW[TPB];

    float S[BINS];
#pragma unroll
    for (int b = 0; b < BINS; ++b) S[b] = 0.0f;
    int C0 = 0;
    unsigned cLo = 0u, cHi = 0u;

    const int nvec = n >> 2;
    // contiguous chunk per block (2048 blocks -> exactly 2560 vec4 = 10 stages)
    const int start = (int)(((long long)nvec * blockIdx.x) / gridDim.x);
    const int end   = (int)(((long long)nvec * (blockIdx.x + 1)) / gridDim.x);
    const int cnt4  = end - start;

    const float4* p4 = (const float4*)pred;
    const float4* t4 = (const float4*)targ;
    const float4* w4 = (const float4*)lw;

    const int wbase   = ((int)threadIdx.x >> 6) << 6;  // wave-uniform LDS base
    const int nstages = (cnt4 + TPB - 1) / TPB;        // block-uniform

    for (int s = 0; s < nstages; ++s) {
        const int idx  = start + s * TPB + (int)threadIdx.x;
        const bool live = (idx < end);
        if (live) {
            glds16(p4 + idx, (void*)&sP[wbase]);
            glds16(t4 + idx, (void*)&sT[wbase]);
            glds16(w4 + idx, (void*)&sW[wbase]);
        }
        __syncthreads();   // drains vmcnt(0): stage data landed in LDS
        if (live) {
            float4 p = sP[threadIdx.x];
            float4 t = sT[threadIdx.x];
            float4 w = sW[threadIdx.x];
            GHMC_ELEM4(p, t, w);
        }
        __syncthreads();   // all reads done before next stage overwrites
    }

    // scalar tail (n not divisible by 4)
    {
        int rem  = n & 3;
        int gtid = blockIdx.x * TPB + (int)threadIdx.x;
        if (gtid < rem) {
            int idx = (nvec << 2) + gtid;
            float pk = pred[idx], tk = targ[idx], wk = lw[idx];
            GHMC_ELEM(pk, tk, wk);
        }
    }

    // per-lane cumulative -> per-bin
    float lsum[BINS];
    int   lcnt[BINS];
    {
        int Cc[BINS];
        Cc[0] = C0;
#pragma unroll
        for (int b = 1; b <= 5; ++b) Cc[b] = (int)((cLo >> (6 * (b - 1))) & 63u);
#pragma unroll
        for (int b = 6; b <= 9; ++b) Cc[b] = (int)((cHi >> (6 * (b - 6))) & 63u);
#pragma unroll
        for (int b = 0; b < BINS - 1; ++b) {
            lsum[b] = S[b] - S[b + 1];
            lcnt[b] = Cc[b] - Cc[b + 1];
        }
        lsum[BINS - 1] = S[BINS - 1];
        lcnt[BINS - 1] = Cc[BINS - 1];
    }

    // ---- wave butterfly, block LDS, one global atomic per bin ----
    __shared__ float s_bsum[BINS];
    __shared__ int   s_bcnt[BINS];
    __shared__ int   s_last;
    if (threadIdx.x < BINS) { s_bsum[threadIdx.x] = 0.0f; s_bcnt[threadIdx.x] = 0; }
    __syncthreads();

    const int lane = threadIdx.x & 63;
#pragma unroll
    for (int b = 0; b < BINS; ++b) {
        float s = lsum[b];
        int   c = lcnt[b];
#pragma unroll
        for (int off = 32; off > 0; off >>= 1) {
            s += __shfl_xor(s, off, 64);
            c += __shfl_xor(c, off, 64);
        }
        if (lane == 0 && c != 0) {
            atomicAdd(&s_bsum[b], s);
            atomicAdd(&s_bcnt[b], c);
        }
    }
    __syncthreads();

    if (threadIdx.x < BINS) {
        float s = s_bsum[threadIdx.x];
        int   c = s_bcnt[threadIdx.x];
        if (c != 0) {
            atomicAdd(&bsum[threadIdx.x], s);   // device-scope by default
            atomicAdd(&bcnt[threadIdx.x], c);
        }
    }
    __threadfence();      // release: this block's global atomics visible
    __syncthreads();      // whole block done + fenced

    // ---- last-block-done: finalize fused into main ----
    if (threadIdx.x == 0) {
        unsigned old = atomicAdd(ticket, 1u);
        s_last = (old == (unsigned)(gridDim.x - 1)) ? 1 : 0;
    }
    __syncthreads();

    if (s_last && threadIdx.x == 0) {
        __threadfence();  // acquire: all other blocks' atomics visible
        float acc = 0.0f;
        int nb = 0;
#pragma unroll
        for (int b = 0; b < BINS; ++b) {
            int c = atomicAdd(&bcnt[b], 0);           // device-coherent read
            if (c > 0) {
                float s = atomicAdd(&bsum[b], 0.0f);  // device-coherent read
                nb += 1;
                acc += s / (float)c;
            }
        }
        out[0] = (nb > 0) ? (acc / (float)nb) : 0.0f;  // LOSS_WEIGHT = 1
    }
}

extern "C" void kernel_launch(void* const* d_in, const int* in_sizes, int n_in,
                              void* d_out, int out_size, void* d_ws, size_t ws_size,
                              hipStream_t stream) {
    const float* pred = (const float*)d_in[0];
    const float* targ = (const float*)d_in[1];
    const float* lw   = (const float*)d_in[2];
    float* out = (float*)d_out;
    const int n = in_sizes[0];   // 262144*80 = 20,971,520

    unsigned* ticket = (unsigned*)d_ws;
    float*    bsum   = (float*)((char*)d_ws + 4);
    int*      bcnt   = (int*)((char*)d_ws + 4 + BINS * sizeof(float));

    ghmc_zero<<<1, 64, 0, stream>>>((unsigned*)d_ws);

    ghmc_main<<<NBLK, TPB, 0, stream>>>(pred, targ, lw,
                                        ticket, bsum, bcnt, out, n);
}